// Round 11
// baseline (749.023 us; speedup 1.0000x reference)
//
#include <hip/hip_runtime.h>
#include <hip/hip_bf16.h>
#include <cstdint>
#include <cstddef>

typedef __attribute__((ext_vector_type(8))) short short8v;
typedef __attribute__((ext_vector_type(4))) int   i32x4;

__device__ __forceinline__ short f2bf(float f) {
    union { float f; unsigned u; } c; c.f = f;
    unsigned r = c.u + 0x7FFFu + ((c.u >> 16) & 1u);
    return (short)(r >> 16);
}

__device__ __forceinline__ float bf2f(ushort u) {
    union { unsigned u; float f; } c; c.u = ((unsigned)u) << 16;
    return c.f;
}

__device__ __forceinline__ void load_lds_16B(const void* g, void* l) {
    __builtin_amdgcn_global_load_lds(
        (const __attribute__((address_space(1))) void*)g,
        (__attribute__((address_space(3))) void*)l, 16, 0, 0);
}

// ---------------- merged per-row int8 quantization of all 4 inputs ----------------
// blocks: [0,2048) s_in K=2048 | [2048,4096) t_in K=4096 | [4096,36096) s_w |
// [36096,68096) t_w.  Block 0 zeroes accum, completion counter, row-sum arrays.
__global__ __launch_bounds__(256)
void quant_all_kernel(const float* __restrict__ s_in, const float* __restrict__ t_in,
                      const float* __restrict__ s_w,  const float* __restrict__ t_w,
                      uint8_t* __restrict__ s_in_q, uint8_t* __restrict__ t_in_q,
                      uint8_t* __restrict__ s_w_q,  uint8_t* __restrict__ t_w_q,
                      float* __restrict__ sa_s, float* __restrict__ sa_t,
                      float* __restrict__ sw_s, float* __restrict__ sw_t,
                      float* __restrict__ sums, double* __restrict__ accum,
                      unsigned* __restrict__ counter)
{
    const int b = blockIdx.x;
    const int tid = threadIdx.x;
    if (b == 0) {
        if (tid == 0) { accum[0] = 0.0; accum[1] = 0.0; *counter = 0u; }
#pragma unroll
        for (int k = 0; k < 24; ++k)        // 256*24 = 6144 floats
            sums[tid * 24 + k] = 0.0f;
    }

    const float* src; uint8_t* dst; float* sc; int R, row;
    if (b < 2048)       { src = s_in; dst = s_in_q; sc = sa_s; R = 2048; row = b; }
    else if (b < 4096)  { src = t_in; dst = t_in_q; sc = sa_t; R = 4096; row = b - 2048; }
    else if (b < 36096) { src = s_w;  dst = s_w_q;  sc = sw_s; R = 2048; row = b - 4096; }
    else                { src = t_w;  dst = t_w_q;  sc = sw_t; R = 4096; row = b - 36096; }

    const float* x = src + (size_t)row * R;
    const int ng = R >> 10;          // 2 or 4

    float4 v[4];
    float am = 0.f;
#pragma unroll
    for (int g = 0; g < 4; ++g) {
        if (g < ng) {
            v[g] = *reinterpret_cast<const float4*>(&x[g * 1024 + tid * 4]);
            am = fmaxf(am, fmaxf(fmaxf(fabsf(v[g].x), fabsf(v[g].y)),
                                 fmaxf(fabsf(v[g].z), fabsf(v[g].w))));
        }
    }
#pragma unroll
    for (int off = 32; off > 0; off >>= 1)
        am = fmaxf(am, __shfl_xor(am, off));
    __shared__ float wam[4];
    if ((tid & 63) == 0) wam[tid >> 6] = am;
    __syncthreads();
    am = fmaxf(fmaxf(wam[0], wam[1]), fmaxf(wam[2], wam[3]));
    am = fmaxf(am, 1e-20f);
    const float inv = 127.0f / am;
    if (tid == 0) sc[row] = am / 127.0f;

    uint32_t* out = (uint32_t*)(dst + (size_t)row * R);
#pragma unroll
    for (int g = 0; g < 4; ++g) {
        if (g < ng) {
            int q0 = __float2int_rn(v[g].x * inv);
            int q1 = __float2int_rn(v[g].y * inv);
            int q2 = __float2int_rn(v[g].z * inv);
            int q3 = __float2int_rn(v[g].w * inv);
            q0 = min(127, max(-127, q0)); q1 = min(127, max(-127, q1));
            q2 = min(127, max(-127, q2)); q3 = min(127, max(-127, q3));
            out[g * 256 + tid] = (q0 & 255) | ((q1 & 255) << 8) |
                                 ((q2 & 255) << 16) | ((uint32_t)(q3 & 255) << 24);
        }
    }
}

// ---------------- 256x256 8-phase int8 GEMM (T1..T5), bf16 C + fused LSE sums ----------------
// Verified round-6 K-loop. MERGED SEQUENTIAL dispatch (round-9 measured best,
// 683 vs 712-714 for split): grid 2000, blocks [0,1000) teacher (K=4096, long,
// LPT-first), [1000,2000) student (K=2048) filling the teacher drain tail.
// 1 block/CU (128 KiB LDS) so blocks never share a CU; merged wins on wall
// time despite lower per-dispatch MfmaUtil (ramp/drain averaging artifact).
// Epilogue: dequant+bias -> bf16 LDS (verified swizzle) + per-row Σexp(v/2)
// [and Σexp(v) via e*e for student], 16-lane shuffle reduce, one float
// atomicAdd per row — logits are N(0,1)-scale, fp32 needs no max shift.

#define SEG_A0 0
#define SEG_A1 32768
#define SEG_B0 65536
#define SEG_B1 98304

#define READ_B_ALL(bseg) do {                                                  \
    _Pragma("unroll")                                                          \
    for (int nf = 0; nf < 4; ++nf) {                                           \
        const int rb = (bseg) + brow + nf * 2048;                              \
        bfr[nf][0] = *(const i32x4*)&sh[rb + c16a];                            \
        bfr[nf][1] = *(const i32x4*)&sh[rb + c16b];                            \
    }                                                                          \
} while (0)

#define READ_A2(aseg, mfb) do {                                                \
    _Pragma("unroll")                                                          \
    for (int d = 0; d < 2; ++d) {                                              \
        const int ra = (aseg) + arow + ((mfb) + d) * 2048;                     \
        af[d][0] = *(const i32x4*)&sh[ra + c16a];                              \
        af[d][1] = *(const i32x4*)&sh[ra + c16b];                              \
    }                                                                          \
} while (0)

#define MFMA16(mfb) do {                                                       \
    __builtin_amdgcn_s_setprio(1);                                             \
    _Pragma("unroll")                                                          \
    for (int d = 0; d < 2; ++d) {                                              \
        _Pragma("unroll")                                                      \
        for (int nf = 0; nf < 4; ++nf) {                                       \
            acc[(mfb)+d][nf] = __builtin_amdgcn_mfma_i32_16x16x64_i8(          \
                af[d][0], bfr[nf][0], acc[(mfb)+d][nf], 0, 0, 0);              \
            acc[(mfb)+d][nf] = __builtin_amdgcn_mfma_i32_16x16x64_i8(          \
                af[d][1], bfr[nf][1], acc[(mfb)+d][nf], 0, 0, 0);              \
        }                                                                      \
    }                                                                          \
    __builtin_amdgcn_s_setprio(0);                                             \
} while (0)

#define BAR() __builtin_amdgcn_s_barrier()
#define VMCNT4() asm volatile("s_waitcnt vmcnt(4)" ::: "memory")
#define VMCNT0() asm volatile("s_waitcnt vmcnt(0)" ::: "memory")

__global__ __launch_bounds__(512, 2)
void gemm256_i8_seq_kernel(const uint8_t* __restrict__ At, const uint8_t* __restrict__ Wt,
                           const float* __restrict__ sat, const float* __restrict__ swt,
                           const float* __restrict__ bt,  ushort* __restrict__ Ct,
                           float* __restrict__ sumh_t,
                           const uint8_t* __restrict__ As, const uint8_t* __restrict__ Ws,
                           const float* __restrict__ sas, const float* __restrict__ sws,
                           const float* __restrict__ bs,  ushort* __restrict__ Cs,
                           float* __restrict__ sumh_s, float* __restrict__ sum1_s,
                           int V)
{
    __shared__ uint8_t sh[131072];   // 128 KiB
    ushort* shs = (ushort*)sh;

    const int tid  = threadIdx.x;
    const int lane = tid & 63;
    const int wave = tid >> 6;
    const int wm = wave >> 2;      // 0..1
    const int wn = wave & 3;       // 0..3

    // sequential population split; per-half bijective XCD swizzle (1000 % 8 == 0)
    const int half = (int)(gridDim.x >> 1);       // 1000
    const int cpx  = half >> 3;                   // 125
    const bool teacher = (int)blockIdx.x < half;
    const int b2 = teacher ? (int)blockIdx.x : (int)blockIdx.x - half;
    const int wg = (b2 & 7) * cpx + (b2 >> 3);
    const int row0 = (wg & 7) * 256;
    const int col0 = (wg >> 3) * 256;

    const uint8_t* A; const uint8_t* W; const float* sa; const float* sw;
    const float* bias; ushort* C; float* sumh; float* sum1; int K;
    if (teacher) { A = At; W = Wt; sa = sat; sw = swt; bias = bt; C = Ct;
                   sumh = sumh_t; sum1 = nullptr; K = 4096; }
    else         { A = As; W = Ws; sa = sas; sw = sws; bias = bs; C = Cs;
                   sumh = sumh_s; sum1 = sum1_s; K = 2048; }

    const int NT = K >> 7;         // K-tiles of 128 i8
    const int NI = NT >> 1;

    const int sr  = lane >> 3;
    const int scb = ((lane & 7) ^ sr) * 16;     // inverse-swizzled byte col
    const size_t a_off = (size_t)(row0 + wave * 8 + sr) * K + scb;
    const size_t w_off = (size_t)(col0 + wave * 8 + sr) * K + scb;
    const int lds_u = wave * 1024;

    auto stage_half = [&](const uint8_t* gb, size_t goff, int seg, int h, int k0) {
        const uint8_t* g0 = gb + goff + (size_t)(h * 128) * K + k0;
        load_lds_16B(g0,                  &sh[seg + h * 16384 + lds_u]);
        load_lds_16B(g0 + (size_t)64 * K, &sh[seg + h * 16384 + 8192 + lds_u]);
    };

    const int l15  = lane & 15;
    const int c16a = (((lane >> 4)    ) ^ (lane & 7)) * 16;
    const int c16b = (((lane >> 4) + 4) ^ (lane & 7)) * 16;
    const int arow = (wm * 128 + l15) * 128;
    const int brow = (wn * 64  + l15) * 128;

    i32x4 acc[8][4];
#pragma unroll
    for (int m = 0; m < 8; ++m)
#pragma unroll
        for (int n = 0; n < 4; ++n)
            acc[m][n] = (i32x4)(0);

    i32x4 bfr[4][2];
    i32x4 af[2][2];

    // ---- prologue
    stage_half(A, a_off, SEG_A0, 0, 0);
    stage_half(A, a_off, SEG_A0, 1, 0);
    stage_half(W, w_off, SEG_B0, 0, 0);
    stage_half(W, w_off, SEG_B0, 1, 0);
    stage_half(W, w_off, SEG_B1, 0, 128);
    stage_half(W, w_off, SEG_B1, 1, 128);
    VMCNT4();
    BAR();

    // ---- main loop
    for (int i = 0; i < NI - 1; ++i) {
        const int kA1 = (2 * i + 1) * 128;
        const int kN2 = (2 * i + 2) * 128;
        const int kB3 = (2 * i + 3) * 128;

        READ_B_ALL(SEG_B0); READ_A2(SEG_A0, 0);
        stage_half(A, a_off, SEG_A1, 0, kA1);
        BAR(); MFMA16(0); BAR();

        READ_A2(SEG_A0, 2);
        stage_half(A, a_off, SEG_A1, 1, kA1);
        BAR(); MFMA16(2); BAR();

        READ_A2(SEG_A0, 4);
        stage_half(W, w_off, SEG_B0, 0, kN2);
        BAR(); MFMA16(4); BAR();

        READ_A2(SEG_A0, 6);
        stage_half(W, w_off, SEG_B0, 1, kN2);
        BAR(); MFMA16(6);
        VMCNT4();
        BAR();

        READ_B_ALL(SEG_B1); READ_A2(SEG_A1, 0);
        stage_half(A, a_off, SEG_A0, 0, kN2);
        BAR(); MFMA16(0); BAR();

        READ_A2(SEG_A1, 2);
        stage_half(A, a_off, SEG_A0, 1, kN2);
        BAR(); MFMA16(2); BAR();

        READ_A2(SEG_A1, 4);
        stage_half(W, w_off, SEG_B1, 0, kB3);
        BAR(); MFMA16(4); BAR();

        READ_A2(SEG_A1, 6);
        stage_half(W, w_off, SEG_B1, 1, kB3);
        BAR(); MFMA16(6);
        VMCNT4();
        BAR();
    }

    // ---- tail iter (tiles NT-2, NT-1)
    {
        const int kA1 = (NT - 1) * 128;
        READ_B_ALL(SEG_B0); READ_A2(SEG_A0, 0);
        stage_half(A, a_off, SEG_A1, 0, kA1);
        BAR(); MFMA16(0); BAR();
        READ_A2(SEG_A0, 2);
        stage_half(A, a_off, SEG_A1, 1, kA1);
        BAR(); MFMA16(2); BAR();
        READ_A2(SEG_A0, 4); BAR(); MFMA16(4); BAR();
        READ_A2(SEG_A0, 6); BAR(); MFMA16(6);
        VMCNT0();
        BAR();
        READ_B_ALL(SEG_B1); READ_A2(SEG_A1, 0); BAR(); MFMA16(0); BAR();
        READ_A2(SEG_A1, 2); BAR(); MFMA16(2); BAR();
        READ_A2(SEG_A1, 4); BAR(); MFMA16(4); BAR();
        READ_A2(SEG_A1, 6); BAR(); MFMA16(6);
    }

    // ---- epilogue: dequant + bias -> bf16 LDS (verified swizzle) + fused LSE sums
    float bb[4], swv[4];
#pragma unroll
    for (int nf = 0; nf < 4; ++nf) {
        const int gc = col0 + wn * 64 + nf * 16 + l15;
        bb[nf]  = bias[gc];
        swv[nf] = sw[gc];
    }

    __syncthreads();   // all ds_reads consumed (vmcnt 0): sh reusable
#pragma unroll
    for (int mf = 0; mf < 8; ++mf) {
        const int rl = wm * 128 + mf * 16 + (lane >> 4) * 4;
        const float4 sav = *reinterpret_cast<const float4*>(&sa[row0 + rl]);
        const float* savp = (const float*)&sav;
#pragma unroll
        for (int j = 0; j < 4; ++j) {
            const int row = rl + j;
            float ph = 0.f, p1 = 0.f;
#pragma unroll
            for (int nf = 0; nf < 4; ++nf) {
                const int cl = wn * 64 + nf * 16 + l15;
                const float v = (float)acc[mf][nf][j] * (savp[j] * swv[nf]) + bb[nf];
                const float e = __expf(0.5f * v);
                ph += e;
                p1 += e * e;
                const int pc = (((cl >> 3) ^ (((row >> 2) & 3) << 1)) << 3) + (cl & 7);
                shs[row * 256 + pc] = (ushort)f2bf(v);
            }
#pragma unroll
            for (int m = 1; m < 16; m <<= 1) {
                ph += __shfl_xor(ph, m);
                p1 += __shfl_xor(p1, m);
            }
            if (l15 == 0) {
                atomicAdd(&sumh[row0 + row], ph);
                if (sum1) atomicAdd(&sum1[row0 + row], p1);
            }
        }
    }
    __syncthreads();
#pragma unroll
    for (int pass = 0; pass < 16; ++pass) {
        const int r = pass * 16 + (tid >> 5);
        const int pc16 = (tid & 31) ^ (((r >> 2) & 3) << 1);
        *reinterpret_cast<short8v*>(&C[(size_t)(row0 + r) * V + col0 + (tid & 31) * 8]) =
            *reinterpret_cast<const short8v*>(&shs[r * 256 + pc16 * 8]);
    }
}

// ---------------- streaming JSD + CE + fused finalize (completion counter) ----------------
__global__ __launch_bounds__(1024)
void jsd_kernel(const ushort* __restrict__ S, const ushort* __restrict__ Tm,
                const float* __restrict__ sum1_s, const float* __restrict__ sumh_s,
                const float* __restrict__ sumh_t, const int* __restrict__ tgt,
                double* __restrict__ accum, unsigned* __restrict__ counter,
                float* __restrict__ out, int V, int nblocks)
{
    const int r = blockIdx.x;
    const ushort* s = S  + (size_t)r * V;
    const ushort* t = Tm + (size_t)r * V;
    const int tid = threadIdx.x;

    const float ls1 = __logf(sum1_s[r]);   // lse_s (T=1)
    const float ls2 = __logf(sumh_s[r]);   // lse_s (T=2)
    const float lt2 = __logf(sumh_t[r]);   // lse_t (T=2)

    float local = 0.f;
#pragma unroll
    for (int it = 0; it < 4; ++it) {
        const int v = it * 8192 + tid * 8;
        if (v < V) {
            short8v sv = *reinterpret_cast<const short8v*>(&s[v]);
            short8v tv = *reinterpret_cast<const short8v*>(&t[v]);
#pragma unroll
            for (int j = 0; j < 8; ++j) {
                float sp = 0.5f * bf2f((ushort)sv[j]) - ls2;
                float tp = 0.5f * bf2f((ushort)tv[j]) - lt2;
                float p = __expf(sp), q = __expf(tp);
                float mm = 0.5f * (p + q);
                float lm = __logf(fmaxf(mm, 1e-38f));
                local += 0.5f * (p * (sp - lm) + q * (tp - lm));
            }
        }
    }
#pragma unroll
    for (int off = 32; off > 0; off >>= 1)
        local += __shfl_xor(local, off);
    __shared__ float ls[16];
    if ((tid & 63) == 0) ls[tid >> 6] = local;
    __syncthreads();
    if (tid == 0) {
        float blocksum = 0.f;
#pragma unroll
        for (int w = 0; w < 16; ++w) blocksum += ls[w];
        atomicAdd(&accum[1], (double)blocksum);
        int tg = tgt[r];
        if (tg != -100) {
            float nll = -(bf2f(s[tg]) - ls1);
            atomicAdd(&accum[0], (double)nll);
        }
        // completion-counter finalize: last block writes the output
        __threadfence();
        unsigned done = atomicAdd(counter, 1u);
        if (done == (unsigned)(nblocks - 1)) {
            __threadfence();
            double inv_n = 1.0 / (double)nblocks;
            out[0] = (float)(0.5 * (accum[0] * inv_n) + 0.5 * (accum[1] * inv_n));
        }
    }
}

extern "C" void kernel_launch(void* const* d_in, const int* in_sizes, int n_in,
                              void* d_out, int out_size, void* d_ws, size_t ws_size,
                              hipStream_t stream)
{
    const float* s_in = (const float*)d_in[0];   // [N, 2048]
    const float* s_w  = (const float*)d_in[1];   // [V, 2048]
    const float* s_b  = (const float*)d_in[2];   // [V]
    const float* t_in = (const float*)d_in[3];   // [N, 4096]
    const float* t_w  = (const float*)d_in[4];   // [V, 4096]
    const float* t_b  = (const float*)d_in[5];   // [V]
    const int*   tgt  = (const int*)d_in[6];     // [N]

    const int N = 2048, V = 32000, KS = 2048, KT = 4096;

    const size_t e_sin = (size_t)N * KS;          // 4,194,304
    const size_t e_sw  = (size_t)V * KS;          // 65,536,000
    const size_t e_tin = (size_t)N * KT;          // 8,388,608
    const size_t e_tw  = (size_t)V * KT;          // 131,072,000

    char* ws = (char*)d_ws;
    double* accum = (double*)ws;                  // 16 B
    unsigned* counter = (unsigned*)(ws + 64);

    // scale arrays: 68096 floats @ ws+4096
    float* sa_s = (float*)(ws + 4096);
    float* sa_t = sa_s + 2048;
    float* sw_s = sa_t + 2048;
    float* sw_t = sw_s + 32000;
    // row-sum arrays (zeroed by quant block 0): 3 x 2048 floats
    float* sum1_s = (float*)(ws + 276480);
    float* sumh_s = sum1_s + 2048;
    float* sumh_t = sumh_s + 2048;
    // int8 data (4096-aligned)
    uint8_t* s_in_q = (uint8_t*)(ws + 303104);
    uint8_t* s_w_q  = s_in_q + e_sin;
    uint8_t* t_in_q = s_w_q + e_sw;
    uint8_t* t_w_q  = t_in_q + e_tin;
    // bf16 logits
    ushort* s_log = (ushort*)(t_w_q + e_tw);
    ushort* t_log = s_log + (size_t)N * V;

    quant_all_kernel<<<68096, 256, 0, stream>>>(
        s_in, t_in, s_w, t_w,
        s_in_q, t_in_q, s_w_q, t_w_q,
        sa_s, sa_t, sw_s, sw_t, sum1_s, accum, counter);

    const int grid = 2 * (V / 256) * (N / 256);   // 2000: [0,1000) teacher, rest student
    gemm256_i8_seq_kernel<<<grid, 512, 0, stream>>>(
        t_in_q, t_w_q, sa_t, sw_t, t_b, t_log, sumh_t,
        s_in_q, s_w_q, sa_s, sw_s, s_b, s_log, sumh_s, sum1_s, V);

    jsd_kernel<<<N, 1024, 0, stream>>>(
        s_log, t_log, sum1_s, sumh_s, sumh_t, tgt, accum, counter,
        (float*)d_out, V, N);
}

// Round 12
// 680.735 us; speedup vs baseline: 1.1003x; 1.1003x over previous
//
#include <hip/hip_runtime.h>
#include <hip/hip_bf16.h>
#include <cstdint>
#include <cstddef>

typedef __attribute__((ext_vector_type(8))) short short8v;
typedef __attribute__((ext_vector_type(4))) int   i32x4;

__device__ __forceinline__ short f2bf(float f) {
    union { float f; unsigned u; } c; c.f = f;
    unsigned r = c.u + 0x7FFFu + ((c.u >> 16) & 1u);
    return (short)(r >> 16);
}

__device__ __forceinline__ float bf2f(ushort u) {
    union { unsigned u; float f; } c; c.u = ((unsigned)u) << 16;
    return c.f;
}

__device__ __forceinline__ void load_lds_16B(const void* g, void* l) {
    __builtin_amdgcn_global_load_lds(
        (const __attribute__((address_space(1))) void*)g,
        (__attribute__((address_space(3))) void*)l, 16, 0, 0);
}

// ---------------- merged per-row int8 quantization of all 4 inputs ----------------
// blocks: [0,2048) s_in K=2048 | [2048,4096) t_in K=4096 | [4096,36096) s_w |
// [36096,68096) t_w.  Block 0 also zeroes accum + the 3 row-sum arrays (6144 f).
__global__ __launch_bounds__(256)
void quant_all_kernel(const float* __restrict__ s_in, const float* __restrict__ t_in,
                      const float* __restrict__ s_w,  const float* __restrict__ t_w,
                      uint8_t* __restrict__ s_in_q, uint8_t* __restrict__ t_in_q,
                      uint8_t* __restrict__ s_w_q,  uint8_t* __restrict__ t_w_q,
                      float* __restrict__ sa_s, float* __restrict__ sa_t,
                      float* __restrict__ sw_s, float* __restrict__ sw_t,
                      float* __restrict__ sums, double* __restrict__ accum)
{
    const int b = blockIdx.x;
    const int tid = threadIdx.x;
    if (b == 0) {
        if (tid == 0) { accum[0] = 0.0; accum[1] = 0.0; }
#pragma unroll
        for (int k = 0; k < 24; ++k)        // 256*24 = 6144 floats
            sums[tid * 24 + k] = 0.0f;
    }

    const float* src; uint8_t* dst; float* sc; int R, row;
    if (b < 2048)       { src = s_in; dst = s_in_q; sc = sa_s; R = 2048; row = b; }
    else if (b < 4096)  { src = t_in; dst = t_in_q; sc = sa_t; R = 4096; row = b - 2048; }
    else if (b < 36096) { src = s_w;  dst = s_w_q;  sc = sw_s; R = 2048; row = b - 4096; }
    else                { src = t_w;  dst = t_w_q;  sc = sw_t; R = 4096; row = b - 36096; }

    const float* x = src + (size_t)row * R;
    const int ng = R >> 10;          // 2 or 4

    float4 v[4];
    float am = 0.f;
#pragma unroll
    for (int g = 0; g < 4; ++g) {
        if (g < ng) {
            v[g] = *reinterpret_cast<const float4*>(&x[g * 1024 + tid * 4]);
            am = fmaxf(am, fmaxf(fmaxf(fabsf(v[g].x), fabsf(v[g].y)),
                                 fmaxf(fabsf(v[g].z), fabsf(v[g].w))));
        }
    }
#pragma unroll
    for (int off = 32; off > 0; off >>= 1)
        am = fmaxf(am, __shfl_xor(am, off));
    __shared__ float wam[4];
    if ((tid & 63) == 0) wam[tid >> 6] = am;
    __syncthreads();
    am = fmaxf(fmaxf(wam[0], wam[1]), fmaxf(wam[2], wam[3]));
    am = fmaxf(am, 1e-20f);
    const float inv = 127.0f / am;
    if (tid == 0) sc[row] = am / 127.0f;

    uint32_t* out = (uint32_t*)(dst + (size_t)row * R);
#pragma unroll
    for (int g = 0; g < 4; ++g) {
        if (g < ng) {
            int q0 = __float2int_rn(v[g].x * inv);
            int q1 = __float2int_rn(v[g].y * inv);
            int q2 = __float2int_rn(v[g].z * inv);
            int q3 = __float2int_rn(v[g].w * inv);
            q0 = min(127, max(-127, q0)); q1 = min(127, max(-127, q1));
            q2 = min(127, max(-127, q2)); q3 = min(127, max(-127, q3));
            out[g * 256 + tid] = (q0 & 255) | ((q1 & 255) << 8) |
                                 ((q2 & 255) << 16) | ((uint32_t)(q3 & 255) << 24);
        }
    }
}

// ---------------- 256x256 8-phase int8 GEMM (T1..T5), bf16 C + fused LSE sums ----------------
// Verified round-6 K-loop, unchanged. Merged SEQUENTIAL launch (round-9 measured
// best, 683): grid 2000, blocks [0,1000) teacher (K=4096, LPT-first),
// [1000,2000) student (K=2048) filling the teacher drain tail.
// Epilogue accumulates per-row Σexp(logit/2) (and Σexp(logit) for student) via
// 16-lane shuffle reduce + float atomicAdd — logits are N(0,1)-scale so fp32
// needs no max-shift.

#define SEG_A0 0
#define SEG_A1 32768
#define SEG_B0 65536
#define SEG_B1 98304

#define READ_B_ALL(bseg) do {                                                  \
    _Pragma("unroll")                                                          \
    for (int nf = 0; nf < 4; ++nf) {                                           \
        const int rb = (bseg) + brow + nf * 2048;                              \
        bfr[nf][0] = *(const i32x4*)&sh[rb + c16a];                            \
        bfr[nf][1] = *(const i32x4*)&sh[rb + c16b];                            \
    }                                                                          \
} while (0)

#define READ_A2(aseg, mfb) do {                                                \
    _Pragma("unroll")                                                          \
    for (int d = 0; d < 2; ++d) {                                              \
        const int ra = (aseg) + arow + ((mfb) + d) * 2048;                     \
        af[d][0] = *(const i32x4*)&sh[ra + c16a];                              \
        af[d][1] = *(const i32x4*)&sh[ra + c16b];                              \
    }                                                                          \
} while (0)

#define MFMA16(mfb) do {                                                       \
    __builtin_amdgcn_s_setprio(1);                                             \
    _Pragma("unroll")                                                          \
    for (int d = 0; d < 2; ++d) {                                              \
        _Pragma("unroll")                                                      \
        for (int nf = 0; nf < 4; ++nf) {                                       \
            acc[(mfb)+d][nf] = __builtin_amdgcn_mfma_i32_16x16x64_i8(          \
                af[d][0], bfr[nf][0], acc[(mfb)+d][nf], 0, 0, 0);              \
            acc[(mfb)+d][nf] = __builtin_amdgcn_mfma_i32_16x16x64_i8(          \
                af[d][1], bfr[nf][1], acc[(mfb)+d][nf], 0, 0, 0);              \
        }                                                                      \
    }                                                                          \
    __builtin_amdgcn_s_setprio(0);                                             \
} while (0)

#define BAR() __builtin_amdgcn_s_barrier()
#define VMCNT4() asm volatile("s_waitcnt vmcnt(4)" ::: "memory")
#define VMCNT0() asm volatile("s_waitcnt vmcnt(0)" ::: "memory")

__global__ __launch_bounds__(512, 2)
void gemm256_i8_seq_kernel(const uint8_t* __restrict__ At, const uint8_t* __restrict__ Wt,
                           const float* __restrict__ sat, const float* __restrict__ swt,
                           const float* __restrict__ bt,  ushort* __restrict__ Ct,
                           float* __restrict__ sumh_t,
                           const uint8_t* __restrict__ As, const uint8_t* __restrict__ Ws,
                           const float* __restrict__ sas, const float* __restrict__ sws,
                           const float* __restrict__ bs,  ushort* __restrict__ Cs,
                           float* __restrict__ sumh_s, float* __restrict__ sum1_s,
                           int V)
{
    __shared__ uint8_t sh[131072];   // 128 KiB
    ushort* shs = (ushort*)sh;

    const int tid  = threadIdx.x;
    const int lane = tid & 63;
    const int wave = tid >> 6;
    const int wm = wave >> 2;      // 0..1
    const int wn = wave & 3;       // 0..3

    // sequential population split; per-half bijective XCD swizzle (1000 % 8 == 0)
    const int half = (int)(gridDim.x >> 1);       // 1000
    const int cpx  = half >> 3;                   // 125
    const bool teacher = (int)blockIdx.x < half;
    const int b2 = teacher ? (int)blockIdx.x : (int)blockIdx.x - half;
    const int wg = (b2 & 7) * cpx + (b2 >> 3);
    const int row0 = (wg & 7) * 256;
    const int col0 = (wg >> 3) * 256;

    const uint8_t* A; const uint8_t* W; const float* sa; const float* sw;
    const float* bias; ushort* C; float* sumh; float* sum1; int K;
    if (teacher) { A = At; W = Wt; sa = sat; sw = swt; bias = bt; C = Ct;
                   sumh = sumh_t; sum1 = nullptr; K = 4096; }
    else         { A = As; W = Ws; sa = sas; sw = sws; bias = bs; C = Cs;
                   sumh = sumh_s; sum1 = sum1_s; K = 2048; }

    const int NT = K >> 7;         // K-tiles of 128 i8
    const int NI = NT >> 1;

    const int sr  = lane >> 3;
    const int scb = ((lane & 7) ^ sr) * 16;     // inverse-swizzled byte col
    const size_t a_off = (size_t)(row0 + wave * 8 + sr) * K + scb;
    const size_t w_off = (size_t)(col0 + wave * 8 + sr) * K + scb;
    const int lds_u = wave * 1024;

    auto stage_half = [&](const uint8_t* gb, size_t goff, int seg, int h, int k0) {
        const uint8_t* g0 = gb + goff + (size_t)(h * 128) * K + k0;
        load_lds_16B(g0,                  &sh[seg + h * 16384 + lds_u]);
        load_lds_16B(g0 + (size_t)64 * K, &sh[seg + h * 16384 + 8192 + lds_u]);
    };

    const int l15  = lane & 15;
    const int c16a = (((lane >> 4)    ) ^ (lane & 7)) * 16;
    const int c16b = (((lane >> 4) + 4) ^ (lane & 7)) * 16;
    const int arow = (wm * 128 + l15) * 128;
    const int brow = (wn * 64  + l15) * 128;

    i32x4 acc[8][4];
#pragma unroll
    for (int m = 0; m < 8; ++m)
#pragma unroll
        for (int n = 0; n < 4; ++n)
            acc[m][n] = (i32x4)(0);

    i32x4 bfr[4][2];
    i32x4 af[2][2];

    // ---- prologue
    stage_half(A, a_off, SEG_A0, 0, 0);
    stage_half(A, a_off, SEG_A0, 1, 0);
    stage_half(W, w_off, SEG_B0, 0, 0);
    stage_half(W, w_off, SEG_B0, 1, 0);
    stage_half(W, w_off, SEG_B1, 0, 128);
    stage_half(W, w_off, SEG_B1, 1, 128);
    VMCNT4();
    BAR();

    // ---- main loop
    for (int i = 0; i < NI - 1; ++i) {
        const int kA1 = (2 * i + 1) * 128;
        const int kN2 = (2 * i + 2) * 128;
        const int kB3 = (2 * i + 3) * 128;

        READ_B_ALL(SEG_B0); READ_A2(SEG_A0, 0);
        stage_half(A, a_off, SEG_A1, 0, kA1);
        BAR(); MFMA16(0); BAR();

        READ_A2(SEG_A0, 2);
        stage_half(A, a_off, SEG_A1, 1, kA1);
        BAR(); MFMA16(2); BAR();

        READ_A2(SEG_A0, 4);
        stage_half(W, w_off, SEG_B0, 0, kN2);
        BAR(); MFMA16(4); BAR();

        READ_A2(SEG_A0, 6);
        stage_half(W, w_off, SEG_B0, 1, kN2);
        BAR(); MFMA16(6);
        VMCNT4();
        BAR();

        READ_B_ALL(SEG_B1); READ_A2(SEG_A1, 0);
        stage_half(A, a_off, SEG_A0, 0, kN2);
        BAR(); MFMA16(0); BAR();

        READ_A2(SEG_A1, 2);
        stage_half(A, a_off, SEG_A0, 1, kN2);
        BAR(); MFMA16(2); BAR();

        READ_A2(SEG_A1, 4);
        stage_half(W, w_off, SEG_B1, 0, kB3);
        BAR(); MFMA16(4); BAR();

        READ_A2(SEG_A1, 6);
        stage_half(W, w_off, SEG_B1, 1, kB3);
        BAR(); MFMA16(6);
        VMCNT4();
        BAR();
    }

    // ---- tail iter (tiles NT-2, NT-1)
    {
        const int kA1 = (NT - 1) * 128;
        READ_B_ALL(SEG_B0); READ_A2(SEG_A0, 0);
        stage_half(A, a_off, SEG_A1, 0, kA1);
        BAR(); MFMA16(0); BAR();
        READ_A2(SEG_A0, 2);
        stage_half(A, a_off, SEG_A1, 1, kA1);
        BAR(); MFMA16(2); BAR();
        READ_A2(SEG_A0, 4); BAR(); MFMA16(4); BAR();
        READ_A2(SEG_A0, 6); BAR(); MFMA16(6);
        VMCNT0();
        BAR();
        READ_B_ALL(SEG_B1); READ_A2(SEG_A1, 0); BAR(); MFMA16(0); BAR();
        READ_A2(SEG_A1, 2); BAR(); MFMA16(2); BAR();
        READ_A2(SEG_A1, 4); BAR(); MFMA16(4); BAR();
        READ_A2(SEG_A1, 6); BAR(); MFMA16(6);
    }

    // ---- epilogue: dequant + bias -> bf16 LDS (verified swizzle) + fused LSE sums
    float bb[4], swv[4];
#pragma unroll
    for (int nf = 0; nf < 4; ++nf) {
        const int gc = col0 + wn * 64 + nf * 16 + l15;
        bb[nf]  = bias[gc];
        swv[nf] = sw[gc];
    }

    __syncthreads();   // all ds_reads consumed (vmcnt 0): sh reusable
#pragma unroll
    for (int mf = 0; mf < 8; ++mf) {
        const int rl = wm * 128 + mf * 16 + (lane >> 4) * 4;
        const float4 sav = *reinterpret_cast<const float4*>(&sa[row0 + rl]);
        const float* savp = (const float*)&sav;
#pragma unroll
        for (int j = 0; j < 4; ++j) {
            const int row = rl + j;
            float ph = 0.f, p1 = 0.f;
#pragma unroll
            for (int nf = 0; nf < 4; ++nf) {
                const int cl = wn * 64 + nf * 16 + l15;
                const float v = (float)acc[mf][nf][j] * (savp[j] * swv[nf]) + bb[nf];
                const float e = __expf(0.5f * v);
                ph += e;
                p1 += e * e;
                const int pc = (((cl >> 3) ^ (((row >> 2) & 3) << 1)) << 3) + (cl & 7);
                shs[row * 256 + pc] = (ushort)f2bf(v);
            }
            // reduce over the 16 lanes sharing this row (lane&15 = col slot)
#pragma unroll
            for (int m = 1; m < 16; m <<= 1) {
                ph += __shfl_xor(ph, m);
                p1 += __shfl_xor(p1, m);
            }
            if (l15 == 0) {
                atomicAdd(&sumh[row0 + row], ph);
                if (sum1) atomicAdd(&sum1[row0 + row], p1);
            }
        }
    }
    __syncthreads();
#pragma unroll
    for (int pass = 0; pass < 16; ++pass) {
        const int r = pass * 16 + (tid >> 5);
        const int pc16 = (tid & 31) ^ (((r >> 2) & 3) << 1);
        *reinterpret_cast<short8v*>(&C[(size_t)(row0 + r) * V + col0 + (tid & 31) * 8]) =
            *reinterpret_cast<const short8v*>(&shs[r * 256 + pc16 * 8]);
    }
}

// ---------------- streaming JSD + CE (LSEs precomputed by GEMM epilogue) ----------------
__global__ __launch_bounds__(1024)
void jsd_kernel(const ushort* __restrict__ S, const ushort* __restrict__ Tm,
                const float* __restrict__ sum1_s, const float* __restrict__ sumh_s,
                const float* __restrict__ sumh_t, const int* __restrict__ tgt,
                double* __restrict__ accum, int V)
{
    const int r = blockIdx.x;
    const ushort* s = S  + (size_t)r * V;
    const ushort* t = Tm + (size_t)r * V;
    const int tid = threadIdx.x;

    const float ls1 = __logf(sum1_s[r]);   // lse_s (T=1)
    const float ls2 = __logf(sumh_s[r]);   // lse_s (T=2)
    const float lt2 = __logf(sumh_t[r]);   // lse_t (T=2)

    float local = 0.f;
#pragma unroll
    for (int it = 0; it < 4; ++it) {
        const int v = it * 8192 + tid * 8;
        if (v < V) {
            short8v sv = *reinterpret_cast<const short8v*>(&s[v]);
            short8v tv = *reinterpret_cast<const short8v*>(&t[v]);
#pragma unroll
            for (int j = 0; j < 8; ++j) {
                float sp = 0.5f * bf2f((ushort)sv[j]) - ls2;
                float tp = 0.5f * bf2f((ushort)tv[j]) - lt2;
                float p = __expf(sp), q = __expf(tp);
                float mm = 0.5f * (p + q);
                float lm = __logf(fmaxf(mm, 1e-38f));
                local += 0.5f * (p * (sp - lm) + q * (tp - lm));
            }
        }
    }
#pragma unroll
    for (int off = 32; off > 0; off >>= 1)
        local += __shfl_xor(local, off);
    __shared__ float ls[16];
    if ((tid & 63) == 0) ls[tid >> 6] = local;
    __syncthreads();
    if (tid == 0) {
        float blocksum = 0.f;
#pragma unroll
        for (int w = 0; w < 16; ++w) blocksum += ls[w];
        atomicAdd(&accum[1], (double)blocksum);
        int tg = tgt[r];
        if (tg != -100) {
            float nll = -(bf2f(s[tg]) - ls1);
            atomicAdd(&accum[0], (double)nll);
        }
    }
}

__global__ void finalize_kernel(const double* __restrict__ accum,
                                float* __restrict__ out, double inv_n) {
    out[0] = (float)(0.5 * (accum[0] * inv_n) + 0.5 * (accum[1] * inv_n));
}

extern "C" void kernel_launch(void* const* d_in, const int* in_sizes, int n_in,
                              void* d_out, int out_size, void* d_ws, size_t ws_size,
                              hipStream_t stream)
{
    const float* s_in = (const float*)d_in[0];   // [N, 2048]
    const float* s_w  = (const float*)d_in[1];   // [V, 2048]
    const float* s_b  = (const float*)d_in[2];   // [V]
    const float* t_in = (const float*)d_in[3];   // [N, 4096]
    const float* t_w  = (const float*)d_in[4];   // [V, 4096]
    const float* t_b  = (const float*)d_in[5];   // [V]
    const int*   tgt  = (const int*)d_in[6];     // [N]

    const int N = 2048, V = 32000, KS = 2048, KT = 4096;

    const size_t e_sin = (size_t)N * KS;          // 4,194,304
    const size_t e_sw  = (size_t)V * KS;          // 65,536,000
    const size_t e_tin = (size_t)N * KT;          // 8,388,608
    const size_t e_tw  = (size_t)V * KT;          // 131,072,000

    char* ws = (char*)d_ws;
    double* accum = (double*)ws;

    // scale arrays: 68096 floats @ ws+4096 .. ws+276480
    float* sa_s = (float*)(ws + 4096);
    float* sa_t = sa_s + 2048;
    float* sw_s = sa_t + 2048;
    float* sw_t = sw_s + 32000;
    // row-sum arrays (zeroed by quant block 0): 3 x 2048 floats
    float* sum1_s = (float*)(ws + 276480);
    float* sumh_s = sum1_s + 2048;
    float* sumh_t = sumh_s + 2048;
    // int8 data (4096-aligned)
    uint8_t* s_in_q = (uint8_t*)(ws + 303104);
    uint8_t* s_w_q  = s_in_q + e_sin;
    uint8_t* t_in_q = s_w_q + e_sw;
    uint8_t* t_w_q  = t_in_q + e_tin;
    // bf16 logits
    ushort* s_log = (ushort*)(t_w_q + e_tw);
    ushort* t_log = s_log + (size_t)N * V;

    quant_all_kernel<<<68096, 256, 0, stream>>>(
        s_in, t_in, s_w, t_w,
        s_in_q, t_in_q, s_w_q, t_w_q,
        sa_s, sa_t, sw_s, sw_t, sum1_s, accum);

    const int grid = 2 * (V / 256) * (N / 256);   // 2000: [0,1000) teacher, rest student
    gemm256_i8_seq_kernel<<<grid, 512, 0, stream>>>(
        t_in_q, t_w_q, sa_t, sw_t, t_b, t_log, sumh_t,
        s_in_q, s_w_q, sa_s, sw_s, s_b, s_log, sumh_s, sum1_s, V);

    jsd_kernel<<<N, 1024, 0, stream>>>(s_log, t_log, sum1_s, sumh_s, sumh_t, tgt, accum, V);

    finalize_kernel<<<1, 1, 0, stream>>>(accum, (float*)d_out, 1.0 / (double)N);
}